// Round 16
// baseline (1414.987 us; speedup 1.0000x reference)
//
#include <hip/hip_runtime.h>
#include <math.h>

typedef unsigned short u16;
typedef short bf16x8 __attribute__((ext_vector_type(8)));
typedef float f32x4 __attribute__((ext_vector_type(4)));
typedef float f32x2 __attribute__((ext_vector_type(2)));

__device__ __forceinline__ float bf2f(u16 h) {
    union { unsigned u; float f; } v; v.u = ((unsigned)h) << 16; return v.f;
}
__device__ __forceinline__ u16 f2bf(float f) {
    union { float f; unsigned u; } v; v.f = f;
    unsigned r = v.u + 0x7fffu + ((v.u >> 16) & 1u);
    return (u16)(r >> 16);
}
__device__ __forceinline__ f32x2 up2(unsigned u) {
    union { unsigned v; float f; } lo, hi;
    lo.v = u << 16; hi.v = u & 0xffff0000u;
    f32x2 r; r.x = lo.f; r.y = hi.f; return r;
}
__device__ __forceinline__ f32x2 unpk(unsigned u) { return up2(u); }
__device__ __forceinline__ f32x4 unpk(uint2 u) {
    f32x2 a = up2(u.x), b = up2(u.y);
    f32x4 r; r.x = a.x; r.y = a.y; r.z = b.x; r.w = b.y; return r;
}
__device__ __forceinline__ unsigned pkbf(f32x2 v) {
    return (unsigned)f2bf(v.x) | ((unsigned)f2bf(v.y) << 16);
}
__device__ __forceinline__ uint2 pkbf(f32x4 v) {
    uint2 r;
    r.x = (unsigned)f2bf(v.x) | ((unsigned)f2bf(v.y) << 16);
    r.y = (unsigned)f2bf(v.z) | ((unsigned)f2bf(v.w) << 16);
    return r;
}
__device__ __forceinline__ float gl(float v) {
    return 0.5f * v * (1.f + erff(v * 0.70710678118654752f));
}

// async global->LDS 16B: LDS dest must be wave-uniform; HW adds lane*16
__device__ __forceinline__ void gload_lds16(const u16* g, u16* l) {
    __builtin_amdgcn_global_load_lds(
        (const __attribute__((address_space(1))) void*)g,
        (__attribute__((address_space(3))) void*)l, 16, 0, 0);
}

template<int N> struct VecT;
template<> struct VecT<2> { typedef f32x2 T; typedef unsigned U; };
template<> struct VecT<4> { typedef f32x4 T; typedef uint2 U; };

#define CH    512
#define NPIX  16384
#define PTOT  32768
#define NHEAD 8

// ---------------- fp32 transpose [R][Cc] -> [Cc][R] per z slab ----------------
__global__ void transpose_k(const float* __restrict__ in, float* outF, u16* outB,
                            int R, int Cc, size_t ibs, size_t obs)
{
    __shared__ float tile[32][33];
    int z = blockIdx.z;
    const float* ip = in + (size_t)z * ibs;
    int c0 = blockIdx.x * 32, r0 = blockIdx.y * 32;
    int tx = threadIdx.x, ty = threadIdx.y;
#pragma unroll
    for (int j = 0; j < 4; j++)
        tile[ty + j * 8][tx] = ip[(size_t)(r0 + ty + j * 8) * Cc + c0 + tx];
    __syncthreads();
#pragma unroll
    for (int j = 0; j < 4; j++) {
        int orow = c0 + ty + j * 8, ocol = r0 + tx;
        float v = tile[tx][ty + j * 8];
        size_t o = (size_t)z * obs + (size_t)orow * R + ocol;
        if (outF) outF[o] = v;
        if (outB) outB[o] = f2bf(v);
    }
}

// ---------------- bf16 transpose [R][Cc] -> [Cc][R] per z slab ----------------
__global__ void transpose16_k(const u16* __restrict__ in, u16* __restrict__ out,
                              int R, int Cc, size_t ibs, size_t obs)
{
    __shared__ u16 tile[32][34];
    int z = blockIdx.z;
    const u16* ip = in + (size_t)z * ibs;
    int c0 = blockIdx.x * 32, r0 = blockIdx.y * 32;
    int tx = threadIdx.x, ty = threadIdx.y;
#pragma unroll
    for (int j = 0; j < 4; j++)
        tile[ty + j * 8][tx] = ip[(size_t)(r0 + ty + j * 8) * Cc + c0 + tx];
    __syncthreads();
#pragma unroll
    for (int j = 0; j < 4; j++)
        out[(size_t)z * obs + (size_t)(c0 + ty + j * 8) * R + r0 + tx] = tile[tx][ty + j * 8];
}

// ---------------- fp32 -> bf16 convert (4 elems/thread) ----------------
__global__ void cvt_bf16_k(const float* __restrict__ in, u16* __restrict__ out)
{
    size_t i = ((size_t)blockIdx.x * 256 + threadIdx.x) * 4;
    float4 v = *(const float4*)&in[i];
    uint2 st;
    st.x = (unsigned)f2bf(v.x) | ((unsigned)f2bf(v.y) << 16);
    st.y = (unsigned)f2bf(v.z) | ((unsigned)f2bf(v.w) << 16);
    *(uint2*)&out[i] = st;
}

// ---- w2 cols 512..2047 -> W2b cols 0..1535 ([g1|g2|g3], plain bf16 cvt) ----
__global__ void cvtw2_k(const float* __restrict__ in, u16* __restrict__ out)
{
    size_t t = (size_t)blockIdx.x * 256 + threadIdx.x;
    size_t i = t * 4;                         // over 2*512*1536
    int l  = (int)(i / 786432);
    int rem = (int)(i - (size_t)l * 786432);
    int o  = rem / 1536;
    int cp = rem - o * 1536;
    float4 v = *(const float4*)&in[(size_t)l * 1048576 + (size_t)o * 2048 + 512 + cp];
    uint2 st;
    st.x = (unsigned)f2bf(v.x) | ((unsigned)f2bf(v.y) << 16);
    st.y = (unsigned)f2bf(v.z) | ((unsigned)f2bf(v.w) << 16);
    *(uint2*)&out[(size_t)l * 1048576 + (size_t)o * 2048 + cp] = st;
}

// ---- w2 g0 cols (0..511) with (1+dw1) prescale -> bf16 [2][512][512] ----
__global__ void cvtw2g0_k(const float* __restrict__ w2, const float* __restrict__ dw1,
                          u16* __restrict__ out)
{
    size_t i = ((size_t)blockIdx.x * 256 + threadIdx.x) * 4;  // over 2*512*512
    int c = (int)(i & 511);
    int o = (int)((i >> 9) & 511);
    int l = (int)(i >> 18);
    float4 v = *(const float4*)&w2[(size_t)l * 1048576 + (size_t)o * 2048 + c];
    v.x *= 1.f + dw1[l * 512 + c];
    v.y *= 1.f + dw1[l * 512 + c + 1];
    v.z *= 1.f + dw1[l * 512 + c + 2];
    v.w *= 1.f + dw1[l * 512 + c + 3];
    uint2 st;
    st.x = (unsigned)f2bf(v.x) | ((unsigned)f2bf(v.y) << 16);
    st.y = (unsigned)f2bf(v.z) | ((unsigned)f2bf(v.w) << 16);
    *(uint2*)&out[i] = st;
}

// ---- copy bf16 slab [16384][512] -> Y2 cols 1536..2047 (stride 2048) ----
__global__ void xcopy_k(const u16* __restrict__ in, u16* __restrict__ out)
{
    size_t i = ((size_t)blockIdx.x * 256 + threadIdx.x) * 8;  // over 16384*512
    int row = (int)(i >> 9), col = (int)(i & 511);
    *(uint4*)&out[(size_t)row * 2048 + 1536 + col] = *(const uint4*)&in[i];
}

// ======== 512-thread 128x128 bf16 NT GEMM: out[i,o]=sum_k A[i,k]*B[o,k] =======
// 3-buffer counted-vmcnt K-loop; pipelined vector epilogue. symTri=1: skip
// strictly-lower 128-tiles of a symmetric per-batch output (bx < by&3).
__global__ __launch_bounds__(512) void gemm5_k(
    const u16* __restrict__ A, const u16* __restrict__ Bw,
    int K, int ldb, int Nn, int rowsPerBatch, int bStride, int kChunk,
    const float* __restrict__ bias, const float* resid,
    float* outF, u16* outB, const u16* __restrict__ addB, int symTri)
{
    __shared__ __attribute__((aligned(16))) u16 smem[6 * 4096];  // A[3]+B[3], 48 KB
    u16* Asb = smem;                 // [3][4096]
    u16* Bsb = smem + 3 * 4096;      // [3][4096]
    int tid = threadIdx.x;

    // ---- XCD-aware bijective swizzle over the (x,y) plane ----
    int gx = gridDim.x;
    int nwg = gx * gridDim.y;
    int lin = blockIdx.y * gx + blockIdx.x;
    int swz = lin;
    if ((nwg & 7) == 0) swz = (lin & 7) * (nwg >> 3) + (lin >> 3);
    int bx = swz % gx, by = swz / gx;

    if (symTri && bx < (by & 3)) return;     // lower triangle tile: mirrored later

    int rowBase = by * 128, colBase = bx * 128;
    const u16* Bp = Bw + (size_t)(rowBase / rowsPerBatch) * bStride;

    int kb = 0, ke = K;
    float* outFp = outF;
    if (kChunk) {
        kb = blockIdx.z * kChunk; ke = kb + kChunk;
        outFp = outF + (size_t)blockIdx.z * (size_t)gridDim.y * 128 * Nn;
    }

    f32x4 acc[4][2] = {};
    int lane = tid & 63, wave = tid >> 6;
    int wr = wave >> 2, wc = wave & 3;       // 2M x 4N wave grid
    int lm = lane & 15, lk = lane >> 4;

    int row0 = tid >> 2;                       // rows 0..127
    int kc   = ((tid ^ (tid >> 3)) & 3) * 8;   // pre-swizzled source k-slot
    int lb0  = (tid & ~63) * 8;                // wave-uniform LDS elem base

    const size_t aR0 = (size_t)(rowBase + row0) * K;
    const size_t bR0 = (size_t)(colBase + row0) * ldb;

    auto STAGE = [&](int bsel, int k0) {
        gload_lds16(&A [aR0 + k0 + kc], Asb + bsel * 4096 + lb0);
        gload_lds16(&Bp[bR0 + k0 + kc], Bsb + bsel * 4096 + lb0);
    };

    const int nsteps = (ke - kb) >> 5;
    STAGE(0, kb);
    STAGE(1, kb + 32);
    const int sl = (lk ^ ((lm >> 1) & 3)) * 8;   // swizzled read slot

    for (int s = 0; s < nsteps; ++s) {
        // tile s landed (own 2 loads, FIFO retire); tile s+1 rides the barrier
        asm volatile("s_waitcnt vmcnt(2)" ::: "memory");
        __builtin_amdgcn_s_barrier();
        __builtin_amdgcn_sched_barrier(0);
        int kpf = kb + ((s + 2 < nsteps) ? (s + 2) : (nsteps - 1)) * 32;
        STAGE((s + 2) % 3, kpf);               // tail: clamped dummy, dead buffer

        const u16* Ab = Asb + (s % 3) * 4096;
        const u16* Bb = Bsb + (s % 3) * 4096;
        bf16x8 af[4], bfr[2];
#pragma unroll
        for (int mt = 0; mt < 4; mt++)
            af[mt] = *(const bf16x8*)&Ab[(wr * 64 + mt * 16 + lm) * 32 + sl];
#pragma unroll
        for (int nt = 0; nt < 2; nt++)
            bfr[nt] = *(const bf16x8*)&Bb[(wc * 32 + nt * 16 + lm) * 32 + sl];
        __builtin_amdgcn_s_setprio(1);
#pragma unroll
        for (int mt = 0; mt < 4; mt++)
#pragma unroll
            for (int nt = 0; nt < 2; nt++)
                acc[mt][nt] = __builtin_amdgcn_mfma_f32_16x16x32_bf16(
                    af[mt], bfr[nt], acc[mt][nt], 0, 0, 0);
        __builtin_amdgcn_s_setprio(0);
    }

    // ---- pipelined vectorized epilogue: LDS transpose, 4 passes of 32 rows ----
    {
        float* smf = (float*)smem;              // 32 x 132 fp32 = 16.9 KB
        constexpr int PADW = 132;
        const int erow = tid >> 5;              // 0..15
        const int ecol = (tid & 31) * 4;        // 0,4,..124
        const int gcol = colBase + ecol;
        f32x4 bv = {};
        if (bias) {
            bv.x = bias[gcol];     bv.y = bias[gcol + 1];
            bv.z = bias[gcol + 2]; bv.w = bias[gcol + 3];
        }
        for (int hf = 0; hf < 4; ++hf) {
            if (hf == 0) {
                __syncthreads();   // drains vmcnt: dummy STAGEs land before reuse
            } else {
                asm volatile("s_waitcnt lgkmcnt(0)" ::: "memory");
                __builtin_amdgcn_s_barrier();
            }
            if (wr == (hf >> 1)) {
                int mtb = (hf & 1) * 2;
#pragma unroll
                for (int m2 = 0; m2 < 2; m2++) {
#pragma unroll
                    for (int nt = 0; nt < 2; nt++) {
                        int lr = m2 * 16 + lk * 4;
                        int lc = wc * 32 + nt * 16 + lm;
#pragma unroll
                        for (int r = 0; r < 4; r++)
                            smf[(lr + r) * PADW + lc] = acc[mtb + m2][nt][r];
                    }
                }
            }
            // issue this pass's global loads; they fly across the raw barrier
            int r0 = rowBase + hf * 32 + erow, r1 = r0 + 16;
            size_t o0 = (size_t)r0 * Nn + gcol, o1 = (size_t)r1 * Nn + gcol;
            f32x4 rv0 = {}, rv1 = {};
            uint2 av0 = {}, av1 = {};
            if (resid) { rv0 = *(const f32x4*)&resid[o0]; rv1 = *(const f32x4*)&resid[o1]; }
            if (addB)  { av0 = *(const uint2*)&addB[o0];  av1 = *(const uint2*)&addB[o1]; }
            asm volatile("s_waitcnt lgkmcnt(0)" ::: "memory");
            __builtin_amdgcn_s_barrier();
            f32x4 v0 = *(f32x4*)&smf[erow * PADW + ecol];
            f32x4 v1 = *(f32x4*)&smf[(erow + 16) * PADW + ecol];
            v0 += bv; v1 += bv;
            if (resid) { v0 += rv0; v1 += rv1; }
            if (addB)  { v0 += unpk(av0); v1 += unpk(av1); }
            if (outFp) { *(f32x4*)&outFp[o0] = v0; *(f32x4*)&outFp[o1] = v1; }
            if (outB) {
                uint2 p0 = pkbf(v0), p1 = pkbf(v1);
                *(uint2*)&outB[o0] = p0; *(uint2*)&outB[o1] = p1;
            }
        }
    }
}

// ------------- 256-thread TM x 128 GEMM (small shapes: T12, M0) -------------
template<int TM, int TN>
__global__ __launch_bounds__(256) void gemm_nt_k(
    const u16* __restrict__ A, const u16* __restrict__ Bw,
    int K, int ldb, int Nn, int rowsPerBatch, int bStride, int kChunk,
    const float* __restrict__ bias, const float* resid,
    float* outF, u16* outB, const u16* __restrict__ addB)
{
    constexpr int MT = TM / 32;
    constexpr int NT = TN / 32;
    constexpr int ABUF = TM * 32;
    constexpr int BBUF = TN * 32;
    __shared__ __attribute__((aligned(16))) u16 smem[2 * ABUF + 2 * BBUF];
    u16* Asb = smem;
    u16* Bsb = smem + 2 * ABUF;
    int tid = threadIdx.x;

    int gx = gridDim.x;
    int nwg = gx * gridDim.y;
    int lin = blockIdx.y * gx + blockIdx.x;
    int swz = lin;
    if ((nwg & 7) == 0) swz = (lin & 7) * (nwg >> 3) + (lin >> 3);
    int bx = swz % gx, by = swz / gx;

    int rowBase = by * TM, colBase = bx * TN;
    const u16* Bp = Bw + (size_t)(rowBase / rowsPerBatch) * bStride;

    int kb = 0, ke = K;
    float* outFp = outF;
    if (kChunk) {
        kb = blockIdx.z * kChunk; ke = kb + kChunk;
        outFp = outF + (size_t)blockIdx.z * (size_t)gridDim.y * TM * Nn;
    }

    f32x4 acc[MT][NT] = {};
    int lane = tid & 63, wave = tid >> 6;
    int wr = wave >> 1, wc = wave & 1;
    int lm = lane & 15, lk = lane >> 4;

    int row0 = tid >> 2;
    int kc   = ((tid ^ (tid >> 3)) & 3) * 8;
    int lb0  = (tid & ~63) * 8;

    const size_t aR0 = (size_t)(rowBase + row0) * K;
    const size_t bR0 = (size_t)(colBase + row0) * ldb;
    const size_t aR1 = (size_t)(rowBase + 64 + row0) * K;
    const size_t bR1 = (size_t)(colBase + 64 + row0) * ldb;

    auto STAGE = [&](int bsel, int k0) {
        gload_lds16(&A [aR0 + k0 + kc], Asb + bsel * ABUF + lb0);
        gload_lds16(&Bp[bR0 + k0 + kc], Bsb + bsel * BBUF + lb0);
        if constexpr (TM == 128)
            gload_lds16(&A [aR1 + k0 + kc], Asb + bsel * ABUF + lb0 + 2048);
        if constexpr (TN == 128)
            gload_lds16(&Bp[bR1 + k0 + kc], Bsb + bsel * BBUF + lb0 + 2048);
    };

    STAGE(0, kb);
    __syncthreads();
    int buf = 0;
    const int sl = (lk ^ ((lm >> 1) & 3)) * 8;

    for (int k0 = kb; k0 < ke; k0 += 32) {
        if (k0 + 32 < ke) STAGE(buf ^ 1, k0 + 32);
        const u16* Ab = Asb + buf * ABUF;
        const u16* Bb = Bsb + buf * BBUF;
        bf16x8 af[MT], bfr[NT];
#pragma unroll
        for (int mt = 0; mt < MT; mt++)
            af[mt] = *(const bf16x8*)&Ab[(wr * (TM / 2) + mt * 16 + lm) * 32 + sl];
#pragma unroll
        for (int nt = 0; nt < NT; nt++)
            bfr[nt] = *(const bf16x8*)&Bb[(wc * (TN / 2) + nt * 16 + lm) * 32 + sl];
#pragma unroll
        for (int mt = 0; mt < MT; mt++)
#pragma unroll
            for (int nt = 0; nt < NT; nt++)
                acc[mt][nt] = __builtin_amdgcn_mfma_f32_16x16x32_bf16(
                    af[mt], bfr[nt], acc[mt][nt], 0, 0, 0);
        __syncthreads();
        buf ^= 1;
    }

    {
        float* smf = (float*)smem;
        constexpr int PADW = TN + 4;
        constexpr int HALVES = TM / 32;
        constexpr int HPW = (MT / 2 > 0) ? MT / 2 : 1;
        const int erow = tid >> 5;
        const int ecol = (tid & 31) * 4;
        for (int hf = 0; hf < HALVES; ++hf) {
            __syncthreads();
            if (wr == hf / HPW) {
                int mtb = (hf % HPW) * 2;
#pragma unroll
                for (int m2 = 0; m2 < 2; m2++) {
#pragma unroll
                    for (int nt = 0; nt < NT; nt++) {
                        int lr = m2 * 16 + lk * 4;
                        int lc = wc * (TN / 2) + nt * 16 + lm;
#pragma unroll
                        for (int r = 0; r < 4; r++)
                            smf[(lr + r) * PADW + lc] = acc[mtb + m2][nt][r];
                    }
                }
            }
            __syncthreads();
#pragma unroll
            for (int p = 0; p < 4; p++) {
                int lrow = erow + p * 8;
                int grow = rowBase + hf * 32 + lrow;
                int gcol = colBase + ecol;
                f32x4 v = *(f32x4*)&smf[lrow * PADW + ecol];
                if (bias) {
                    v.x += bias[gcol];     v.y += bias[gcol + 1];
                    v.z += bias[gcol + 2]; v.w += bias[gcol + 3];
                }
                size_t o = (size_t)grow * Nn + gcol;
                if (resid) { f32x4 rv = *(const f32x4*)&resid[o]; v += rv; }
                if (addB)  { f32x4 av = unpk(*(const uint2*)&addB[o]); v += av; }
                if (outFp) *(f32x4*)&outFp[o] = v;
                if (outB) { uint2 pk = pkbf(v); *(uint2*)&outB[o] = pk; }
            }
        }
    }
}

// ------- reduce 16 split-K partials -> bf16, mirroring lower triangle -------
__global__ void sreduce_k(const float* __restrict__ Sp, u16* __restrict__ Sbf)
{
    int i = blockIdx.x * 256 + threadIdx.x;      // over 2*512*512
    int b = i >> 18, rc = i & 262143, r = rc >> 9, c = rc & 511;
    size_t src = (r > c) ? ((size_t)b << 18) + ((size_t)c << 9) + r : (size_t)i;
    float s = 0.f;
#pragma unroll
    for (int z = 0; z < 16; z++) s += Sp[(size_t)z * 524288 + src];
    Sbf[i] = f2bf(s);
}

// -------- inv l2 norms (Q and K merged; T12f [1024 rows][1024 cols]) --------
// EXACTLY 2048 work items: launch with 8 blocks x 256 threads.
__global__ void nrm_k(const float* __restrict__ Wqf, const float* __restrict__ Wkf,
                      const float* __restrict__ T12f,
                      float* __restrict__ QNI, float* __restrict__ KNI)
{
    int idx = blockIdx.x * 256 + threadIdx.x;   // 0..2047
    int e = idx & 511, b = (idx >> 9) & 1, which = idx >> 10;
    const float* w = which ? Wkf : Wqf;
    const float* Tf = T12f + which * 512;
    float s = 0.f;
    for (int c = 0; c < 512; c++)
        s += w[c * 512 + e] * Tf[(size_t)(b * 512 + c) * 1024 + e];
    s = fmaxf(s, 0.f);
    float* outp = which ? KNI : QNI;
    outp[b * 512 + e] = 1.f / fmaxf(sqrtf(s), 1e-12f);
}

// ---- G[b,h,d,e]=sum_c T2[b,c,h64+d]*Wq[c,h64+e]; scale+softmax (4x4 blocked) ----
__global__ __launch_bounds__(256) void gsmall_k(
    const float* __restrict__ T2f, const float* __restrict__ Wq,
    const float* __restrict__ qinv, const float* __restrict__ kinv,
    const float* __restrict__ resc, float* __restrict__ att)
{
    __shared__ float t2l[64][64], wql[64][64];
    int t = threadIdx.x, h = blockIdx.x, b = blockIdx.y;
    const int eg = (t & 15) * 4;      // e0
    const int dg = (t >> 4) * 4;      // d0
    f32x4 acc[4] = {};                // acc[dj] vector over 4 e
    for (int c0 = 0; c0 < 512; c0 += 64) {
        __syncthreads();
        for (int i = t; i < 4096; i += 256) {
            int cc = i >> 6, j = i & 63;
            t2l[cc][j] = T2f[(size_t)(b * 512 + c0 + cc) * 1024 + h * 64 + j];
            wql[cc][j] = Wq[(size_t)(c0 + cc) * 512 + h * 64 + j];
        }
        __syncthreads();
        for (int cc = 0; cc < 64; cc++) {
            f32x4 qv = *(f32x4*)&wql[cc][eg];
            f32x4 dv = *(f32x4*)&t2l[cc][dg];
            acc[0] += dv.x * qv;
            acc[1] += dv.y * qv;
            acc[2] += dv.z * qv;
            acc[3] += dv.w * qv;
        }
    }
    float rs = resc[h];
    f32x4 qn = *(const f32x4*)&qinv[b * 512 + h * 64 + eg];
    float* ap = att + (size_t)(b * 8 + h) * 4096;
#pragma unroll
    for (int dj = 0; dj < 4; dj++) {
        int d = dg + dj;
        float kn = kinv[b * 512 + h * 64 + d];
        f32x4 v = acc[dj] * kn;
        v = v * qn;
        v.x *= rs; v.y *= rs; v.z *= rs; v.w *= rs;
        float m = fmaxf(fmaxf(v.x, v.y), fmaxf(v.z, v.w));
        for (int off = 1; off <= 8; off <<= 1) m = fmaxf(m, __shfl_xor(m, off));
        f32x4 ev;
        ev.x = expf(v.x - m); ev.y = expf(v.y - m);
        ev.z = expf(v.z - m); ev.w = expf(v.w - m);
        float s = ev.x + ev.y + ev.z + ev.w;
        for (int off = 1; off <= 8; off <<= 1) s += __shfl_xor(s, off);
        f32x4 r;
        r.x = ev.x / s; r.y = ev.y / s; r.z = ev.z / s; r.w = ev.w / s;
        *(f32x4*)&ap[d * 64 + eg] = r;
    }
}

// ---- M[b] fold: grid (8 h, 2 b, 8 ot), 4x4 register blocking ----
__global__ __launch_bounds__(256) void mbuild_k(const float* __restrict__ attn,
                                                const float* __restrict__ projW,
                                                u16* Mnt)
{
    __shared__ float at[64][64];
    __shared__ float pw[64][64];
    int t = threadIdx.x;
    int h = blockIdx.x, b = blockIdx.y, ot = blockIdx.z;
    const float* ap = attn + (size_t)(b * NHEAD + h) * 4096;
    for (int i = t; i < 4096; i += 256) {
        at[i >> 6][i & 63] = ap[i];
        pw[i >> 6][i & 63] = projW[(size_t)(h * 64 + (i >> 6)) * CH + ot * 64 + (i & 63)];
    }
    __syncthreads();
    const int eg = (t & 15) * 4;      // e0
    const int rg = (t >> 4) * 4;      // o0 within this ot block
    f32x4 acc[4] = {};                // acc[j] vector over 4 e
    for (int dd = 0; dd < 64; dd++) {
        f32x4 av = *(f32x4*)&at[dd][eg];
        f32x4 pv = *(f32x4*)&pw[dd][rg];
        acc[0] += pv.x * av;
        acc[1] += pv.y * av;
        acc[2] += pv.z * av;
        acc[3] += pv.w * av;
    }
#pragma unroll
    for (int j = 0; j < 4; j++) {
        uint2 pk = pkbf(acc[j]);
        *(uint2*)&Mnt[(size_t)b * (CH * CH)
                      + (size_t)(ot * 64 + rg + j) * CH + h * 64 + eg] = pk;
    }
}

// ============ register-sliding-window NHWC depthwise conv (pipelined) ============
template<int KS, int YS, int CPT, bool GELU_F, bool RESID, bool ACC, int SI, int SO>
__global__ __launch_bounds__(256, 1) void dwreg_k(
    const u16* __restrict__ in, const float* __restrict__ w,
    u16* __restrict__ outB, float* __restrict__ outAdd)
{
    constexpr int PAD = KS / 2;
    typedef typename VecT<CPT>::T fv;
    typedef typename VecT<CPT>::U uv;
    const int tid = threadIdx.x;
    const int cbase = (CPT == 4) ? ((tid & 127) * 4) : (tid * 2);
    const int x     = (CPT == 4) ? ((int)blockIdx.x * 2 + (tid >> 7)) : (int)blockIdx.x;
    const int y0 = blockIdx.y * YS;
    const int b  = blockIdx.z;
    const size_t bi = (size_t)b * NPIX * SI + cbase;
    const size_t bo = (size_t)b * NPIX * SO + cbase;

    fv wv[KS * KS];
#pragma unroll
    for (int t = 0; t < KS * KS; t++) {
        fv vv;
        vv.x = w[(cbase + 0) * KS * KS + t];
        vv.y = w[(cbase + 1) * KS * KS + t];
        if constexpr (CPT == 4) {
            vv.z = w[(cbase + 2) * KS * KS + t];
            vv.w = w[(cbase + 3) * KS * KS + t];
        }
        wv[t] = vv;
    }

    fv win[KS][KS];
    uv tmp[KS];

    auto rowload = [&](int t) {
        int yy = y0 - PAD + t;
        bool rv = ((unsigned)yy < 128u);
#pragma unroll
        for (int kx = 0; kx < KS; kx++) {
            int xx = x + kx - PAD;
            uv u = {};
            if (rv && ((unsigned)xx < 128u))
                u = *(const uv*)&in[bi + ((size_t)yy * 128 + xx) * SI];
            tmp[kx] = u;
        }
    };
    auto unpackrow = [&](int slot) {
#pragma unroll
        for (int kx = 0; kx < KS; kx++) win[slot][kx] = unpk(tmp[kx]);
    };

#pragma unroll
    for (int t = 0; t < KS - 1; t++) { rowload(t); unpackrow(t); }
    rowload(KS - 1);

    for (int i0 = 0; i0 < YS; i0 += KS) {
#pragma unroll
        for (int j = 0; j < KS; j++) {
            int i = i0 + j;
            if (i >= YS) break;
            unpackrow((j + KS - 1) % KS);
            if (i < YS - 1) rowload(i + KS);
            fv r = {};
#pragma unroll
            for (int ky = 0; ky < KS; ky++)
#pragma unroll
                for (int kx = 0; kx < KS; kx++)
                    r += win[(j + ky) % KS][kx] * wv[ky * KS + kx];
            if (GELU_F) {
                r.x = gl(r.x); r.y = gl(r.y);
                if constexpr (CPT == 4) { r.z = gl(r.z); r.w = gl(r.w); }
            }
            if (RESID) r += win[(j + PAD) % KS][PAD];
            size_t opos = bo + ((size_t)(y0 + i) * 128 + x) * SO;
            if (ACC) {
                fv* p = (fv*)&outAdd[opos];
                *p = *p + r;
            } else {
                uv pk = pkbf(r);
                *(uv*)&outB[opos] = pk;
            }
        }
    }
}

// ---------------- LayerNorm over c=512 per pixel, bf16 out ----------------
__global__ void ln_k(const float* __restrict__ xf, const float* __restrict__ g,
                     const float* __restrict__ bb, u16* __restrict__ xn)
{
    int t = threadIdx.x, lane = t & 63, wv = t >> 6;
    size_t pix = (size_t)blockIdx.x * 4 + wv;
    const float* row = xf + pix * CH;
    float4 a = *(const float4*)&row[lane * 8];
    float4 c = *(const float4*)&row[lane * 8 + 4];
    float s = a.x + a.y + a.z + a.w + c.x + c.y + c.z + c.w;
    float sq = a.x * a.x + a.y * a.y + a.z * a.z + a.w * a.w
             + c.x * c.x + c.y * c.y + c.z * c.z + c.w * c.w;
    for (int off = 32; off; off >>= 1) {
        s  += __shfl_xor(s, off);
        sq += __shfl_xor(sq, off);
    }
    float mu = s * (1.f / 512.f);
    float var = fmaxf(sq * (1.f / 512.f) - mu * mu, 0.f);
    float inv = rsqrtf(var + 1e-5f);
    float vals[8] = {a.x, a.y, a.z, a.w, c.x, c.y, c.z, c.w};
    unsigned o[4];
#pragma unroll
    for (int j = 0; j < 4; j++) {
        int cix = lane * 8 + j * 2;
        float v0 = (vals[j * 2] - mu) * inv * g[cix] + bb[cix];
        float v1 = (vals[j * 2 + 1] - mu) * inv * g[cix + 1] + bb[cix + 1];
        o[j] = (unsigned)f2bf(v0) | ((unsigned)f2bf(v1) << 16);
    }
    *(uint4*)&xn[pix * CH + lane * 8] = make_uint4(o[0], o[1], o[2], o[3]);
}

// =====================================================================
extern "C" void kernel_launch(void* const* d_in, const int* in_sizes, int n_in,
                              void* d_out, int out_size, void* d_ws, size_t ws_size,
                              hipStream_t stream)
{
    (void)in_sizes; (void)n_in; (void)out_size; (void)ws_size;
    const float* x_in  = (const float*)d_in[0];
    const float* Wq    = (const float*)d_in[1];
    const float* Wk    = (const float*)d_in[2];
    const float* Wv    = (const float*)d_in[3];
    const float* resc  = (const float*)d_in[4];
    const float* projW = (const float*)d_in[5];
    const float* projB = (const float*)d_in[6];
    const float* posw1 = (const float*)d_in[7];
    const float* posw2 = (const float*)d_in[8];
    const float* lng   = (const float*)d_in[9];
    const float* lnb   = (const float*)d_in[10];
    const float* w1    = (const float*)d_in[11];
    const float* dw1   = (const float*)d_in[12];
    const float* dw3   = (const float*)d_in[13];
    const float* dw5   = (const float*)d_in[14];
    const float* dw7   = (const float*)d_in[15];
    const float* w2    = (const float*)d_in[16];
    float* out = (float*)d_out;
    char* ws = (char*)d_ws;

    // ---- d_ws layout (~119 MB) ----
    float* XF  = (float*)(ws + 0);               // 64 MB fp32 state [b,n,c]
    u16*   XBb = (u16*)  (ws + 67108864ull);     // 32 MB bf16 x / xn / P [b,n,c]
    u16*   WQK = (u16*)  (ws + 100663296ull);    // 2 MB [2][1024][512] (Wq^T|Wk^T)
    u16*   WVt = (u16*)  (ws + 102760448ull);    // 1 MB
    u16*   W1b = (u16*)  (ws + 103809024ull);    // 4 MB [2][2048][512]
    u16*   W2b = (u16*)  (ws + 108003328ull);    // 4 MB [2][512][2048] = [g1|g2|g3|M0]
    u16*   Mnt = (u16*)  (ws + 112197632ull);    // 1 MB [2][512][512]
    u16*   Sbf = (u16*)  (ws + 113246208ull);    // 1 MB [2][512][512]
    float* QNI = (float*)(ws + 118489088ull);    // 4 KB [2][512]
    float* KNI = (float*)(ws + 118493184ull);    // 4 KB
    float* ATT = (float*)(ws + 118497280ull);    // 256 KB [2][8][64][64]

    // ---- d_out used as scratch until the final transpose ----
    u16*   R2  = (u16*)d_out;                    // 32 MB (attn phase)
    u16*   R3  = (u16*)d_out + 16777216;         // 32 MB (attn phase)
    float* Sp  = (float*)((char*)d_out + 33554432ull); // 32 MB split-K partials (z=16)
    float* T12f= (float*)((char*)d_out + 33554432ull); // 4 MB [1024][1024] (after sreduce)
    u16*   Y2  = (u16*)d_out;                    // FFN: [16384][2048] bf16 (64 MB/batch slab)
    u16*   W2g0ps = (u16*)((char*)d_out + 50331648ull); // 1 MB prep temp (dead later)
    u16*   W1g0T  = (u16*)((char*)d_out + 51380224ull); // 1 MB prep temp (dead later)

    const int BIG = 1 << 30;
    dim3 tb(32, 8);

    // prep
    transpose_k<<<dim3(512, 16, 2), tb, 0, stream>>>(x_in, XF, XBb, 512, 16384, 8388608, 8388608);
    transpose_k<<<dim3(16, 16, 2), tb, 0, stream>>>(Wq, nullptr, WQK, 512, 512, 262144, 524288);
    transpose_k<<<dim3(16, 16, 2), tb, 0, stream>>>(Wk, nullptr, WQK + 262144, 512, 512, 262144, 524288);
    transpose_k<<<dim3(16, 16, 2), tb, 0, stream>>>(Wv, nullptr, WVt, 512, 512, 262144, 262144);
    cvt_bf16_k<<<2048, 256, 0, stream>>>(w1, W1b);
    // FFN weight prep: W2b cols 0..1535 = w2 cols 512..2047 ([g1|g2|g3]);
    // cols 1536..2047 = M0 = (w2 g0-cols * (1+dw1)) @ w1_g0^T (fused g0 path)
    cvtw2_k<<<1536, 256, 0, stream>>>(w2, W2b);
    cvtw2g0_k<<<512, 256, 0, stream>>>(w2, dw1, W2g0ps);
    transpose_k<<<dim3(16, 16, 2), tb, 0, stream>>>(w1, nullptr, W1g0T, 512, 512, 1048576, 262144);
    for (int l = 0; l < 2; l++)
        gemm_nt_k<64, 128><<<dim3(4, 8), 256, 0, stream>>>(W2g0ps + l * 262144,
            W1g0T + l * 262144, 512, 512, 2048, BIG, 0, 0,
            nullptr, nullptr, nullptr, W2b + l * 1048576 + 1536, nullptr);

    for (int l = 0; l < 2; l++) {
        // XT (bf16 [b][c][n]) into R2
        if (l == 0)
            cvt_bf16_k<<<16384, 256, 0, stream>>>(x_in, R2);
        else
            transpose16_k<<<dim3(16, 512, 2), tb, 0, stream>>>(XBb, R2, 16384, 512, 8388608, 8388608);
        // S = X^T X per batch (symmetric: upper tiles only), split-K z=16
        gemm5_k<<<dim3(4, 8, 16), 512, 0, stream>>>(R2, R2, 16384, 16384, 512,
            512, 8388608, 1024, nullptr, nullptr, Sp, nullptr, nullptr, 1);
        sreduce_k<<<2048, 256, 0, stream>>>(Sp, Sbf);
        // T12 = S @ [Wq|Wk]^T  (one N=1024 GEMM into T12f [1024][1024])
        gemm_nt_k<64, 128><<<dim3(8, 16), 256, 0, stream>>>(Sbf, WQK + l * 524288,
            512, 512, 1024, BIG, 0, 0, nullptr, nullptr, T12f, nullptr, nullptr);
        nrm_k<<<8, 256, 0, stream>>>(Wq + l * 262144, Wk + l * 262144, T12f, QNI, KNI);
        gsmall_k<<<dim3(8, 2), 256, 0, stream>>>(T12f + 512, Wq + l * 262144, QNI, KNI,
            resc + l * 8, ATT);
        mbuild_k<<<dim3(8, 2, 8), 256, 0, stream>>>(ATT, projW + l * 262144, Mnt);
        // V = x @ Wv  (512-thread 128x128)
        gemm5_k<<<dim3(4, 256), 512, 0, stream>>>(XBb, WVt + l * 262144, 512, 512, 512,
            BIG, 0, 0, nullptr, nullptr, nullptr, R3, nullptr, 0);
        // positional branch FIRST: conv3+gelu (R3->R2), conv3 -> bf16 P (XBb)
        dwreg_k<3, 16, 4, true, false, false, 512, 512><<<dim3(64, 8, 2), 256, 0, stream>>>(
            R3, posw1 + l * 4608, R2, nullptr);
        dwreg_k<3, 16, 4, false, false, false, 512, 512><<<dim3(64, 8, 2), 256, 0, stream>>>(
            R2, posw2 + l * 4608, XBb, nullptr);
        // x += V @ M^T + proj_b + P   (512-thread, single XF RMW pass)
        gemm5_k<<<dim3(4, 256), 512, 0, stream>>>(R3, Mnt, 512, 512, 512,
            16384, 262144, 0, projB + l * 512, XF, XF, nullptr, XBb, 0);
        // PreNorm
        ln_k<<<8192, 256, 0, stream>>>(XF, lng + l * 512, lnb + l * 512, XBb);
        // MS-FFN: per-batch slabs. ONE N=1536 up-GEMM (g1,g2,g3 = contiguous
        // W1b rows 512..2047) -> Y2 slots 1,2,3 raw; conv cascade through
        // freed slots: conv3 1->0, conv5 2->1, conv7 3->2; xn copy -> slot 3
        // (M0 fold covers g0); single K=2048 down-GEMM.
        for (int b2 = 0; b2 < 2; b2++) {
            const size_t boff = (size_t)b2 * NPIX * 512;
            const u16* w1l = W1b + l * 1048576;
            // up g1+g2+g3 (N=1536) -> slots 1,2,3
            gemm5_k<<<dim3(12, 128), 512, 0, stream>>>(XBb + boff,
                w1l + 512 * 512, 512, 512, 2048,
                BIG, 0, 0, nullptr, nullptr, nullptr, Y2 + 512, nullptr, 0);
            // conv3: slot1 (raw g1) -> slot0
            dwreg_k<3, 16, 4, false, true, false, 2048, 2048><<<dim3(64, 8, 1), 256, 0, stream>>>(
                Y2 + 512, dw3 + l * 4608, Y2 + 0, nullptr);
            // conv5: slot2 (raw g2) -> slot1
            dwreg_k<5, 16, 2, false, true, false, 2048, 2048><<<dim3(128, 8, 1), 256, 0, stream>>>(
                Y2 + 1024, dw5 + l * 12800, Y2 + 512, nullptr);
            // conv7: slot3 (raw g3) -> slot2
            dwreg_k<7, 32, 2, false, true, false, 2048, 2048><<<dim3(128, 4, 1), 256, 0, stream>>>(
                Y2 + 1536, dw7 + l * 25088, Y2 + 1024, nullptr);
            // xn -> slot3 (feeds the M0 columns of W2b)
            xcopy_k<<<4096, 256, 0, stream>>>(XBb + boff, Y2);
            // single K=2048 down-GEMM: XF += Y2 @ W2b^T  (W2b = [g1|g2|g3|M0])
            gemm5_k<<<dim3(4, 128), 512, 0, stream>>>(Y2,
                W2b + l * 1048576, 2048, 2048, 512,
                BIG, 0, 0, nullptr, XF + boff, XF + boff, XBb + boff, nullptr, 0);
        }
    }
    // final: XF [b,n,c] -> out [b,c,n]
    transpose_k<<<dim3(16, 512, 2), tb, 0, stream>>>(XF, out, nullptr, 16384, 512, 8388608, 8388608);
}

// Round 19
// 1355.801 us; speedup vs baseline: 1.0437x; 1.0437x over previous
//
#include <hip/hip_runtime.h>
#include <math.h>

typedef unsigned short u16;
typedef short bf16x8 __attribute__((ext_vector_type(8)));
typedef float f32x4 __attribute__((ext_vector_type(4)));
typedef float f32x2 __attribute__((ext_vector_type(2)));

__device__ __forceinline__ float bf2f(u16 h) {
    union { unsigned u; float f; } v; v.u = ((unsigned)h) << 16; return v.f;
}
__device__ __forceinline__ u16 f2bf(float f) {
    union { float f; unsigned u; } v; v.f = f;
    unsigned r = v.u + 0x7fffu + ((v.u >> 16) & 1u);
    return (u16)(r >> 16);
}
__device__ __forceinline__ f32x2 up2(unsigned u) {
    union { unsigned v; float f; } lo, hi;
    lo.v = u << 16; hi.v = u & 0xffff0000u;
    f32x2 r; r.x = lo.f; r.y = hi.f; return r;
}
__device__ __forceinline__ f32x2 unpk(unsigned u) { return up2(u); }
__device__ __forceinline__ f32x4 unpk(uint2 u) {
    f32x2 a = up2(u.x), b = up2(u.y);
    f32x4 r; r.x = a.x; r.y = a.y; r.z = b.x; r.w = b.y; return r;
}
__device__ __forceinline__ unsigned pkbf(f32x2 v) {
    return (unsigned)f2bf(v.x) | ((unsigned)f2bf(v.y) << 16);
}
__device__ __forceinline__ uint2 pkbf(f32x4 v) {
    uint2 r;
    r.x = (unsigned)f2bf(v.x) | ((unsigned)f2bf(v.y) << 16);
    r.y = (unsigned)f2bf(v.z) | ((unsigned)f2bf(v.w) << 16);
    return r;
}
__device__ __forceinline__ float gl(float v) {
    return 0.5f * v * (1.f + erff(v * 0.70710678118654752f));
}

// async global->LDS 16B: LDS dest must be wave-uniform; HW adds lane*16
__device__ __forceinline__ void gload_lds16(const u16* g, u16* l) {
    __builtin_amdgcn_global_load_lds(
        (const __attribute__((address_space(1))) void*)g,
        (__attribute__((address_space(3))) void*)l, 16, 0, 0);
}

template<int N> struct VecT;
template<> struct VecT<2> { typedef f32x2 T; typedef unsigned U; };
template<> struct VecT<4> { typedef f32x4 T; typedef uint2 U; };

#define CH    512
#define NPIX  16384
#define PTOT  32768
#define NHEAD 8

// ---------------- fp32 transpose [R][Cc] -> [Cc][R] per z slab ----------------
__global__ void transpose_k(const float* __restrict__ in, float* outF, u16* outB,
                            int R, int Cc, size_t ibs, size_t obs)
{
    __shared__ float tile[32][33];
    int z = blockIdx.z;
    const float* ip = in + (size_t)z * ibs;
    int c0 = blockIdx.x * 32, r0 = blockIdx.y * 32;
    int tx = threadIdx.x, ty = threadIdx.y;
#pragma unroll
    for (int j = 0; j < 4; j++)
        tile[ty + j * 8][tx] = ip[(size_t)(r0 + ty + j * 8) * Cc + c0 + tx];
    __syncthreads();
#pragma unroll
    for (int j = 0; j < 4; j++) {
        int orow = c0 + ty + j * 8, ocol = r0 + tx;
        float v = tile[tx][ty + j * 8];
        size_t o = (size_t)z * obs + (size_t)orow * R + ocol;
        if (outF) outF[o] = v;
        if (outB) outB[o] = f2bf(v);
    }
}

// ---------------- bf16 transpose [R][Cc] -> [Cc][R] per z slab ----------------
__global__ void transpose16_k(const u16* __restrict__ in, u16* __restrict__ out,
                              int R, int Cc, size_t ibs, size_t obs)
{
    __shared__ u16 tile[32][34];
    int z = blockIdx.z;
    const u16* ip = in + (size_t)z * ibs;
    int c0 = blockIdx.x * 32, r0 = blockIdx.y * 32;
    int tx = threadIdx.x, ty = threadIdx.y;
#pragma unroll
    for (int j = 0; j < 4; j++)
        tile[ty + j * 8][tx] = ip[(size_t)(r0 + ty + j * 8) * Cc + c0 + tx];
    __syncthreads();
#pragma unroll
    for (int j = 0; j < 4; j++)
        out[(size_t)z * obs + (size_t)(c0 + ty + j * 8) * R + r0 + tx] = tile[tx][ty + j * 8];
}

// ---------------- fp32 -> bf16 convert (4 elems/thread) ----------------
__global__ void cvt_bf16_k(const float* __restrict__ in, u16* __restrict__ out)
{
    size_t i = ((size_t)blockIdx.x * 256 + threadIdx.x) * 4;
    float4 v = *(const float4*)&in[i];
    uint2 st;
    st.x = (unsigned)f2bf(v.x) | ((unsigned)f2bf(v.y) << 16);
    st.y = (unsigned)f2bf(v.z) | ((unsigned)f2bf(v.w) << 16);
    *(uint2*)&out[i] = st;
}

// ---- w2 cols 512..2047 -> W2b cols 0..1535 ([g1|g2|g3], plain bf16 cvt) ----
__global__ void cvtw2_k(const float* __restrict__ in, u16* __restrict__ out)
{
    size_t t = (size_t)blockIdx.x * 256 + threadIdx.x;
    size_t i = t * 4;                         // over 2*512*1536
    int l  = (int)(i / 786432);
    int rem = (int)(i - (size_t)l * 786432);
    int o  = rem / 1536;
    int cp = rem - o * 1536;
    float4 v = *(const float4*)&in[(size_t)l * 1048576 + (size_t)o * 2048 + 512 + cp];
    uint2 st;
    st.x = (unsigned)f2bf(v.x) | ((unsigned)f2bf(v.y) << 16);
    st.y = (unsigned)f2bf(v.z) | ((unsigned)f2bf(v.w) << 16);
    *(uint2*)&out[(size_t)l * 1048576 + (size_t)o * 2048 + cp] = st;
}

// ---- w2 g0 cols (0..511) with (1+dw1) prescale -> bf16 [2][512][512] ----
__global__ void cvtw2g0_k(const float* __restrict__ w2, const float* __restrict__ dw1,
                          u16* __restrict__ out)
{
    size_t i = ((size_t)blockIdx.x * 256 + threadIdx.x) * 4;  // over 2*512*512
    int c = (int)(i & 511);
    int o = (int)((i >> 9) & 511);
    int l = (int)(i >> 18);
    float4 v = *(const float4*)&w2[(size_t)l * 1048576 + (size_t)o * 2048 + c];
    v.x *= 1.f + dw1[l * 512 + c];
    v.y *= 1.f + dw1[l * 512 + c + 1];
    v.z *= 1.f + dw1[l * 512 + c + 2];
    v.w *= 1.f + dw1[l * 512 + c + 3];
    uint2 st;
    st.x = (unsigned)f2bf(v.x) | ((unsigned)f2bf(v.y) << 16);
    st.y = (unsigned)f2bf(v.z) | ((unsigned)f2bf(v.w) << 16);
    *(uint2*)&out[i] = st;
}

// ---- copy bf16 slab [16384][512] -> Y2 cols 1536..2047 (stride 2048) ----
__global__ void xcopy_k(const u16* __restrict__ in, u16* __restrict__ out)
{
    size_t i = ((size_t)blockIdx.x * 256 + threadIdx.x) * 8;  // over 16384*512
    int row = (int)(i >> 9), col = (int)(i & 511);
    *(uint4*)&out[(size_t)row * 2048 + 1536 + col] = *(const uint4*)&in[i];
}

// ======== 512-thread 128x128 bf16 NT GEMM: out[i,o]=sum_k A[i,k]*B[o,k] =======
// 3-buffer counted-vmcnt K-loop; pipelined vector epilogue. Optional A2 kept
// (unused this round: cross-block race when A2 aliases outB — see r18).
__global__ __launch_bounds__(512) void gemm5_k(
    const u16* __restrict__ A, const u16* __restrict__ Bw,
    int K, int ldb, int Nn, int rowsPerBatch, int bStride, int kChunk,
    const float* __restrict__ bias, const float* resid,
    float* outF, u16* outB, const u16* __restrict__ addB,
    const u16* __restrict__ A2)
{
    __shared__ __attribute__((aligned(16))) u16 smem[6 * 4096];  // A[3]+B[3], 48 KB
    u16* Asb = smem;                 // [3][4096]
    u16* Bsb = smem + 3 * 4096;      // [3][4096]
    int tid = threadIdx.x;

    // ---- XCD-aware bijective swizzle over the (x,y) plane ----
    int gx = gridDim.x;
    int nwg = gx * gridDim.y;
    int lin = blockIdx.y * gx + blockIdx.x;
    int swz = lin;
    if ((nwg & 7) == 0) swz = (lin & 7) * (nwg >> 3) + (lin >> 3);
    int bx = swz % gx, by = swz / gx;

    int rowBase = by * 128, colBase = bx * 128;
    const u16* Bp = Bw + (size_t)(rowBase / rowsPerBatch) * bStride;

    int kb = 0, ke = K;
    float* outFp = outF;
    if (kChunk) {
        kb = blockIdx.z * kChunk; ke = kb + kChunk;
        outFp = outF + (size_t)blockIdx.z * (size_t)gridDim.y * 128 * Nn;
    }

    f32x4 acc[4][2] = {};
    int lane = tid & 63, wave = tid >> 6;
    int wr = wave >> 2, wc = wave & 3;       // 2M x 4N wave grid
    int lm = lane & 15, lk = lane >> 4;

    int row0 = tid >> 2;                       // rows 0..127
    int kc   = ((tid ^ (tid >> 3)) & 3) * 8;   // pre-swizzled source k-slot
    int lb0  = (tid & ~63) * 8;                // wave-uniform LDS elem base

    const size_t aR0 = (size_t)(rowBase + row0) * K;
    const size_t a2R0 = (size_t)(rowBase + row0) * 512;
    const size_t bR0 = (size_t)(colBase + row0) * ldb;

    auto STAGE = [&](int bsel, int k0) {
        const u16* asrc = (A2 && k0 >= 1536)
            ? &A2[a2R0 + (k0 - 1536) + kc]
            : &A [aR0 + k0 + kc];
        gload_lds16(asrc, Asb + bsel * 4096 + lb0);
        gload_lds16(&Bp[bR0 + k0 + kc], Bsb + bsel * 4096 + lb0);
    };

    const int nsteps = (ke - kb) >> 5;
    STAGE(0, kb);
    STAGE(1, kb + 32);
    const int sl = (lk ^ ((lm >> 1) & 3)) * 8;   // swizzled read slot

    for (int s = 0; s < nsteps; ++s) {
        // tile s landed (own 2 loads, FIFO retire); tile s+1 rides the barrier
        asm volatile("s_waitcnt vmcnt(2)" ::: "memory");
        __builtin_amdgcn_s_barrier();
        __builtin_amdgcn_sched_barrier(0);
        int kpf = kb + ((s + 2 < nsteps) ? (s + 2) : (nsteps - 1)) * 32;
        STAGE((s + 2) % 3, kpf);               // tail: clamped dummy, dead buffer

        const u16* Ab = Asb + (s % 3) * 4096;
        const u16* Bb = Bsb + (s % 3) * 4096;
        bf16x8 af[4], bfr[2];
#pragma unroll
        for (int mt = 0; mt < 4; mt++)
            af[mt] = *(const bf16x8*)&Ab[(wr * 64 + mt * 16 + lm) * 32 + sl];
#pragma unroll
        for (int nt = 0; nt < 2; nt++)
            bfr[nt] = *(const bf16x8*)&Bb[(wc * 32 + nt * 16 + lm) * 32 + sl];
        __builtin_amdgcn_s_setprio(1);
#pragma unroll
        for (int mt = 0; mt < 4; mt++)
#pragma unroll
            for (int nt = 0; nt < 2; nt++)
                acc[mt][nt] = __builtin_amdgcn_mfma_f32_16x16x32_bf16(
                    af[mt], bfr[nt], acc[mt][nt], 0, 0, 0);
        __builtin_amdgcn_s_setprio(0);
    }

    // ---- pipelined vectorized epilogue: LDS transpose, 4 passes of 32 rows ----
    {
        float* smf = (float*)smem;              // 32 x 132 fp32 = 16.9 KB
        constexpr int PADW = 132;
        const int erow = tid >> 5;              // 0..15
        const int ecol = (tid & 31) * 4;        // 0,4,..124
        const int gcol = colBase + ecol;
        f32x4 bv = {};
        if (bias) {
            bv.x = bias[gcol];     bv.y = bias[gcol + 1];
            bv.z = bias[gcol + 2]; bv.w = bias[gcol + 3];
        }
        for (int hf = 0; hf < 4; ++hf) {
            if (hf == 0) {
                __syncthreads();   // drains vmcnt: dummy STAGEs land before reuse
            } else {
                asm volatile("s_waitcnt lgkmcnt(0)" ::: "memory");
                __builtin_amdgcn_s_barrier();
            }
            if (wr == (hf >> 1)) {
                int mtb = (hf & 1) * 2;
#pragma unroll
                for (int m2 = 0; m2 < 2; m2++) {
#pragma unroll
                    for (int nt = 0; nt < 2; nt++) {
                        int lr = m2 * 16 + lk * 4;
                        int lc = wc * 32 + nt * 16 + lm;
#pragma unroll
                        for (int r = 0; r < 4; r++)
                            smf[(lr + r) * PADW + lc] = acc[mtb + m2][nt][r];
                    }
                }
            }
            // issue this pass's global loads; they fly across the raw barrier
            int r0 = rowBase + hf * 32 + erow, r1 = r0 + 16;
            size_t o0 = (size_t)r0 * Nn + gcol, o1 = (size_t)r1 * Nn + gcol;
            f32x4 rv0 = {}, rv1 = {};
            uint2 av0 = {}, av1 = {};
            if (resid) { rv0 = *(const f32x4*)&resid[o0]; rv1 = *(const f32x4*)&resid[o1]; }
            if (addB)  { av0 = *(const uint2*)&addB[o0];  av1 = *(const uint2*)&addB[o1]; }
            asm volatile("s_waitcnt lgkmcnt(0)" ::: "memory");
            __builtin_amdgcn_s_barrier();
            f32x4 v0 = *(f32x4*)&smf[erow * PADW + ecol];
            f32x4 v1 = *(f32x4*)&smf[(erow + 16) * PADW + ecol];
            v0 += bv; v1 += bv;
            if (resid) { v0 += rv0; v1 += rv1; }
            if (addB)  { v0 += unpk(av0); v1 += unpk(av1); }
            if (outFp) { *(f32x4*)&outFp[o0] = v0; *(f32x4*)&outFp[o1] = v1; }
            if (outB) {
                uint2 p0 = pkbf(v0), p1 = pkbf(v1);
                *(uint2*)&outB[o0] = p0; *(uint2*)&outB[o1] = p1;
            }
        }
    }
}

// ------------- 256-thread TM x 128 GEMM (small shapes: T12, M0) -------------
template<int TM, int TN>
__global__ __launch_bounds__(256) void gemm_nt_k(
    const u16* __restrict__ A, const u16* __restrict__ Bw,
    int K, int ldb, int Nn, int rowsPerBatch, int bStride, int kChunk,
    const float* __restrict__ bias, const float* resid,
    float* outF, u16* outB, const u16* __restrict__ addB)
{
    constexpr int MT = TM / 32;
    constexpr int NT = TN / 32;
    constexpr int ABUF = TM * 32;
    constexpr int BBUF = TN * 32;
    __shared__ __attribute__((aligned(16))) u16 smem[2 * ABUF + 2 * BBUF];
    u16* Asb = smem;
    u16* Bsb = smem + 2 * ABUF;
    int tid = threadIdx.x;

    int gx = gridDim.x;
    int nwg = gx * gridDim.y;
    int lin = blockIdx.y * gx + blockIdx.x;
    int swz = lin;
    if ((nwg & 7) == 0) swz = (lin & 7) * (nwg >> 3) + (lin >> 3);
    int bx = swz % gx, by = swz / gx;

    int rowBase = by * TM, colBase = bx * TN;
    const u16* Bp = Bw + (size_t)(rowBase / rowsPerBatch) * bStride;

    int kb = 0, ke = K;
    float* outFp = outF;
    if (kChunk) {
        kb = blockIdx.z * kChunk; ke = kb + kChunk;
        outFp = outF + (size_t)blockIdx.z * (size_t)gridDim.y * TM * Nn;
    }

    f32x4 acc[MT][NT] = {};
    int lane = tid & 63, wave = tid >> 6;
    int wr = wave >> 1, wc = wave & 1;
    int lm = lane & 15, lk = lane >> 4;

    int row0 = tid >> 2;
    int kc   = ((tid ^ (tid >> 3)) & 3) * 8;
    int lb0  = (tid & ~63) * 8;

    const size_t aR0 = (size_t)(rowBase + row0) * K;
    const size_t bR0 = (size_t)(colBase + row0) * ldb;
    const size_t aR1 = (size_t)(rowBase + 64 + row0) * K;
    const size_t bR1 = (size_t)(colBase + 64 + row0) * ldb;

    auto STAGE = [&](int bsel, int k0) {
        gload_lds16(&A [aR0 + k0 + kc], Asb + bsel * ABUF + lb0);
        gload_lds16(&Bp[bR0 + k0 + kc], Bsb + bsel * BBUF + lb0);
        if constexpr (TM == 128)
            gload_lds16(&A [aR1 + k0 + kc], Asb + bsel * ABUF + lb0 + 2048);
        if constexpr (TN == 128)
            gload_lds16(&Bp[bR1 + k0 + kc], Bsb + bsel * BBUF + lb0 + 2048);
    };

    STAGE(0, kb);
    __syncthreads();
    int buf = 0;
    const int sl = (lk ^ ((lm >> 1) & 3)) * 8;

    for (int k0 = kb; k0 < ke; k0 += 32) {
        if (k0 + 32 < ke) STAGE(buf ^ 1, k0 + 32);
        const u16* Ab = Asb + buf * ABUF;
        const u16* Bb = Bsb + buf * BBUF;
        bf16x8 af[MT], bfr[NT];
#pragma unroll
        for (int mt = 0; mt < MT; mt++)
            af[mt] = *(const bf16x8*)&Ab[(wr * (TM / 2) + mt * 16 + lm) * 32 + sl];
#pragma unroll
        for (int nt = 0; nt < NT; nt++)
            bfr[nt] = *(const bf16x8*)&Bb[(wc * (TN / 2) + nt * 16 + lm) * 32 + sl];
#pragma unroll
        for (int mt = 0; mt < MT; mt++)
#pragma unroll
            for (int nt = 0; nt < NT; nt++)
                acc[mt][nt] = __builtin_amdgcn_mfma_f32_16x16x32_bf16(
                    af[mt], bfr[nt], acc[mt][nt], 0, 0, 0);
        __syncthreads();
        buf ^= 1;
    }

    {
        float* smf = (float*)smem;
        constexpr int PADW = TN + 4;
        constexpr int HALVES = TM / 32;
        constexpr int HPW = (MT / 2 > 0) ? MT / 2 : 1;
        const int erow = tid >> 5;
        const int ecol = (tid & 31) * 4;
        for (int hf = 0; hf < HALVES; ++hf) {
            __syncthreads();
            if (wr == hf / HPW) {
                int mtb = (hf % HPW) * 2;
#pragma unroll
                for (int m2 = 0; m2 < 2; m2++) {
#pragma unroll
                    for (int nt = 0; nt < NT; nt++) {
                        int lr = m2 * 16 + lk * 4;
                        int lc = wc * (TN / 2) + nt * 16 + lm;
#pragma unroll
                        for (int r = 0; r < 4; r++)
                            smf[(lr + r) * PADW + lc] = acc[mtb + m2][nt][r];
                    }
                }
            }
            __syncthreads();
#pragma unroll
            for (int p = 0; p < 4; p++) {
                int lrow = erow + p * 8;
                int grow = rowBase + hf * 32 + lrow;
                int gcol = colBase + ecol;
                f32x4 v = *(f32x4*)&smf[lrow * PADW + ecol];
                if (bias) {
                    v.x += bias[gcol];     v.y += bias[gcol + 1];
                    v.z += bias[gcol + 2]; v.w += bias[gcol + 3];
                }
                size_t o = (size_t)grow * Nn + gcol;
                if (resid) { f32x4 rv = *(const f32x4*)&resid[o]; v += rv; }
                if (addB)  { f32x4 av = unpk(*(const uint2*)&addB[o]); v += av; }
                if (outFp) *(f32x4*)&outFp[o] = v;
                if (outB) { uint2 pk = pkbf(v); *(uint2*)&outB[o] = pk; }
            }
        }
    }
}

// ---------------- reduce 16 split-K partials -> bf16 (coalesced) ----------------
__global__ void sreduce_k(const float* __restrict__ Sp, u16* __restrict__ Sbf)
{
    int i = blockIdx.x * 256 + threadIdx.x;
    float s = 0.f;
#pragma unroll
    for (int z = 0; z < 16; z++) s += Sp[(size_t)z * 524288 + i];
    Sbf[i] = f2bf(s);
}

// -------- inv l2 norms (Q and K merged; T12f [1024 rows][1024 cols]) --------
// EXACTLY 2048 work items: launch with 8 blocks x 256 threads.
__global__ void nrm_k(const float* __restrict__ Wqf, const float* __restrict__ Wkf,
                      const float* __restrict__ T12f,
                      float* __restrict__ QNI, float* __restrict__ KNI)
{
    int idx = blockIdx.x * 256 + threadIdx.x;   // 0..2047
    int e = idx & 511, b = (idx >> 9) & 1, which = idx >> 10;
    const float* w = which ? Wkf : Wqf;
    const float* Tf = T12f + which * 512;
    float s = 0.f;
    for (int c = 0; c < 512; c++)
        s += w[c * 512 + e] * Tf[(size_t)(b * 512 + c) * 1024 + e];
    s = fmaxf(s, 0.f);
    float* outp = which ? KNI : QNI;
    outp[b * 512 + e] = 1.f / fmaxf(sqrtf(s), 1e-12f);
}

// ---- G[b,h,d,e]=sum_c T2[b,c,h64+d]*Wq[c,h64+e]; scale+softmax (4x4 blocked) ----
__global__ __launch_bounds__(256) void gsmall_k(
    const float* __restrict__ T2f, const float* __restrict__ Wq,
    const float* __restrict__ qinv, const float* __restrict__ kinv,
    const float* __restrict__ resc, float* __restrict__ att)
{
    __shared__ float t2l[64][64], wql[64][64];
    int t = threadIdx.x, h = blockIdx.x, b = blockIdx.y;
    const int eg = (t & 15) * 4;      // e0
    const int dg = (t >> 4) * 4;      // d0
    f32x4 acc[4] = {};                // acc[dj] vector over 4 e
    for (int c0 = 0; c0 < 512; c0 += 64) {
        __syncthreads();
        for (int i = t; i < 4096; i += 256) {
            int cc = i >> 6, j = i & 63;
            t2l[cc][j] = T2f[(size_t)(b * 512 + c0 + cc) * 1024 + h * 64 + j];
            wql[cc][j] = Wq[(size_t)(c0 + cc) * 512 + h * 64 + j];
        }
        __syncthreads();
        for (int cc = 0; cc < 64; cc++) {
            f32x4 qv = *(f32x4*)&wql[cc][eg];
            f32x4 dv = *(f32x4*)&t2l[cc][dg];
            acc[0] += dv.x * qv;
            acc[1] += dv.y * qv;
            acc[2] += dv.z * qv;
            acc[3] += dv.w * qv;
        }
    }
    float rs = resc[h];
    f32x4 qn = *(const f32x4*)&qinv[b * 512 + h * 64 + eg];
    float* ap = att + (size_t)(b * 8 + h) * 4096;
#pragma unroll
    for (int dj = 0; dj < 4; dj++) {
        int d = dg + dj;
        float kn = kinv[b * 512 + h * 64 + d];
        f32x4 v = acc[dj] * kn;
        v = v * qn;
        v.x *= rs; v.y *= rs; v.z *= rs; v.w *= rs;
        float m = fmaxf(fmaxf(v.x, v.y), fmaxf(v.z, v.w));
        for (int off = 1; off <= 8; off <<= 1) m = fmaxf(m, __shfl_xor(m, off));
        f32x4 ev;
        ev.x = expf(v.x - m); ev.y = expf(v.y - m);
        ev.z = expf(v.z - m); ev.w = expf(v.w - m);
        float s = ev.x + ev.y + ev.z + ev.w;
        for (int off = 1; off <= 8; off <<= 1) s += __shfl_xor(s, off);
        f32x4 r;
        r.x = ev.x / s; r.y = ev.y / s; r.z = ev.z / s; r.w = ev.w / s;
        *(f32x4*)&ap[d * 64 + eg] = r;
    }
}

// ---- M[b] fold: grid (8 h, 2 b, 8 ot), 4x4 register blocking ----
__global__ __launch_bounds__(256) void mbuild_k(const float* __restrict__ attn,
                                                const float* __restrict__ projW,
                                                u16* Mnt)
{
    __shared__ float at[64][64];
    __shared__ float pw[64][64];
    int t = threadIdx.x;
    int h = blockIdx.x, b = blockIdx.y, ot = blockIdx.z;
    const float* ap = attn + (size_t)(b * NHEAD + h) * 4096;
    for (int i = t; i < 4096; i += 256) {
        at[i >> 6][i & 63] = ap[i];
        pw[i >> 6][i & 63] = projW[(size_t)(h * 64 + (i >> 6)) * CH + ot * 64 + (i & 63)];
    }
    __syncthreads();
    const int eg = (t & 15) * 4;      // e0
    const int rg = (t >> 4) * 4;      // o0 within this ot block
    f32x4 acc[4] = {};                // acc[j] vector over 4 e
    for (int dd = 0; dd < 64; dd++) {
        f32x4 av = *(f32x4*)&at[dd][eg];
        f32x4 pv = *(f32x4*)&pw[dd][rg];
        acc[0] += pv.x * av;
        acc[1] += pv.y * av;
        acc[2] += pv.z * av;
        acc[3] += pv.w * av;
    }
#pragma unroll
    for (int j = 0; j < 4; j++) {
        uint2 pk = pkbf(acc[j]);
        *(uint2*)&Mnt[(size_t)b * (CH * CH)
                      + (size_t)(ot * 64 + rg + j) * CH + h * 64 + eg] = pk;
    }
}

// ============ register-sliding-window NHWC depthwise conv (pipelined) ============
template<int KS, int YS, int CPT, bool GELU_F, bool RESID, bool ACC, int SI, int SO>
__global__ __launch_bounds__(256, 1) void dwreg_k(
    const u16* __restrict__ in, const float* __restrict__ w,
    u16* __restrict__ outB, float* __restrict__ outAdd)
{
    constexpr int PAD = KS / 2;
    typedef typename VecT<CPT>::T fv;
    typedef typename VecT<CPT>::U uv;
    const int tid = threadIdx.x;
    const int cbase = (CPT == 4) ? ((tid & 127) * 4) : (tid * 2);
    const int x     = (CPT == 4) ? ((int)blockIdx.x * 2 + (tid >> 7)) : (int)blockIdx.x;
    const int y0 = blockIdx.y * YS;
    const int b  = blockIdx.z;
    const size_t bi = (size_t)b * NPIX * SI + cbase;
    const size_t bo = (size_t)b * NPIX * SO + cbase;

    fv wv[KS * KS];
#pragma unroll
    for (int t = 0; t < KS * KS; t++) {
        fv vv;
        vv.x = w[(cbase + 0) * KS * KS + t];
        vv.y = w[(cbase + 1) * KS * KS + t];
        if constexpr (CPT == 4) {
            vv.z = w[(cbase + 2) * KS * KS + t];
            vv.w = w[(cbase + 3) * KS * KS + t];
        }
        wv[t] = vv;
    }

    fv win[KS][KS];
    uv tmp[KS];

    auto rowload = [&](int t) {
        int yy = y0 - PAD + t;
        bool rv = ((unsigned)yy < 128u);
#pragma unroll
        for (int kx = 0; kx < KS; kx++) {
            int xx = x + kx - PAD;
            uv u = {};
            if (rv && ((unsigned)xx < 128u))
                u = *(const uv*)&in[bi + ((size_t)yy * 128 + xx) * SI];
            tmp[kx] = u;
        }
    };
    auto unpackrow = [&](int slot) {
#pragma unroll
        for (int kx = 0; kx < KS; kx++) win[slot][kx] = unpk(tmp[kx]);
    };

#pragma unroll
    for (int t = 0; t < KS - 1; t++) { rowload(t); unpackrow(t); }
    rowload(KS - 1);

    for (int i0 = 0; i0 < YS; i0 += KS) {
#pragma unroll
        for (int j = 0; j < KS; j++) {
            int i = i0 + j;
            if (i >= YS) break;
            unpackrow((j + KS - 1) % KS);
            if (i < YS - 1) rowload(i + KS);
            fv r = {};
#pragma unroll
            for (int ky = 0; ky < KS; ky++)
#pragma unroll
                for (int kx = 0; kx < KS; kx++)
                    r += win[(j + ky) % KS][kx] * wv[ky * KS + kx];
            if (GELU_F) {
                r.x = gl(r.x); r.y = gl(r.y);
                if constexpr (CPT == 4) { r.z = gl(r.z); r.w = gl(r.w); }
            }
            if (RESID) r += win[(j + PAD) % KS][PAD];
            size_t opos = bo + ((size_t)(y0 + i) * 128 + x) * SO;
            if (ACC) {
                fv* p = (fv*)&outAdd[opos];
                *p = *p + r;
            } else {
                uv pk = pkbf(r);
                *(uv*)&outB[opos] = pk;
            }
        }
    }
}

// ---------------- LayerNorm over c=512 per pixel, bf16 out ----------------
__global__ void ln_k(const float* __restrict__ xf, const float* __restrict__ g,
                     const float* __restrict__ bb, u16* __restrict__ xn)
{
    int t = threadIdx.x, lane = t & 63, wv = t >> 6;
    size_t pix = (size_t)blockIdx.x * 4 + wv;
    const float* row = xf + pix * CH;
    float4 a = *(const float4*)&row[lane * 8];
    float4 c = *(const float4*)&row[lane * 8 + 4];
    float s = a.x + a.y + a.z + a.w + c.x + c.y + c.z + c.w;
    float sq = a.x * a.x + a.y * a.y + a.z * a.z + a.w * a.w
             + c.x * c.x + c.y * c.y + c.z * c.z + c.w * c.w;
    for (int off = 32; off; off >>= 1) {
        s  += __shfl_xor(s, off);
        sq += __shfl_xor(sq, off);
    }
    float mu = s * (1.f / 512.f);
    float var = fmaxf(sq * (1.f / 512.f) - mu * mu, 0.f);
    float inv = rsqrtf(var + 1e-5f);
    float vals[8] = {a.x, a.y, a.z, a.w, c.x, c.y, c.z, c.w};
    unsigned o[4];
#pragma unroll
    for (int j = 0; j < 4; j++) {
        int cix = lane * 8 + j * 2;
        float v0 = (vals[j * 2] - mu) * inv * g[cix] + bb[cix];
        float v1 = (vals[j * 2 + 1] - mu) * inv * g[cix + 1] + bb[cix + 1];
        o[j] = (unsigned)f2bf(v0) | ((unsigned)f2bf(v1) << 16);
    }
    *(uint4*)&xn[pix * CH + lane * 8] = make_uint4(o[0], o[1], o[2], o[3]);
}

// =====================================================================
extern "C" void kernel_launch(void* const* d_in, const int* in_sizes, int n_in,
                              void* d_out, int out_size, void* d_ws, size_t ws_size,
                              hipStream_t stream)
{
    (void)in_sizes; (void)n_in; (void)out_size; (void)ws_size;
    const float* x_in  = (const float*)d_in[0];
    const float* Wq    = (const float*)d_in[1];
    const float* Wk    = (const float*)d_in[2];
    const float* Wv    = (const float*)d_in[3];
    const float* resc  = (const float*)d_in[4];
    const float* projW = (const float*)d_in[5];
    const float* projB = (const float*)d_in[6];
    const float* posw1 = (const float*)d_in[7];
    const float* posw2 = (const float*)d_in[8];
    const float* lng   = (const float*)d_in[9];
    const float* lnb   = (const float*)d_in[10];
    const float* w1    = (const float*)d_in[11];
    const float* dw1   = (const float*)d_in[12];
    const float* dw3   = (const float*)d_in[13];
    const float* dw5   = (const float*)d_in[14];
    const float* dw7   = (const float*)d_in[15];
    const float* w2    = (const float*)d_in[16];
    float* out = (float*)d_out;
    char* ws = (char*)d_ws;

    // ---- d_ws layout (~119 MB) ----
    float* XF  = (float*)(ws + 0);               // 64 MB fp32 state [b,n,c]
    u16*   XBb = (u16*)  (ws + 67108864ull);     // 32 MB bf16 x / xn / P [b,n,c]
    u16*   WQK = (u16*)  (ws + 100663296ull);    // 2 MB [2][1024][512] (Wq^T|Wk^T)
    u16*   WVt = (u16*)  (ws + 102760448ull);    // 1 MB
    u16*   W1b = (u16*)  (ws + 103809024ull);    // 4 MB [2][2048][512]
    u16*   W2b = (u16*)  (ws + 108003328ull);    // 4 MB [2][512][2048] = [g1|g2|g3|M0]
    u16*   Mnt = (u16*)  (ws + 112197632ull);    // 1 MB [2][512][512]
    u16*   Sbf = (u16*)  (ws + 113246208ull);    // 1 MB [2][512][512]
    float* QNI = (float*)(ws + 118489088ull);    // 4 KB [2][512]
    float* KNI = (float*)(ws + 118493184ull);    // 4 KB
    float* ATT = (float*)(ws + 118497280ull);    // 256 KB [2][8][64][64]

    // ---- d_out used as scratch until the final transpose ----
    u16*   R2  = (u16*)d_out;                    // 32 MB (attn phase)
    u16*   R3  = (u16*)d_out + 16777216;         // 32 MB (attn phase)
    float* Sp  = (float*)((char*)d_out + 33554432ull); // 32 MB split-K partials (z=16)
    float* T12f= (float*)((char*)d_out + 33554432ull); // 4 MB [1024][1024] (after sreduce)
    u16*   Y2  = (u16*)d_out;                    // FFN: [16384][2048] bf16 (64 MB/batch slab)
    u16*   W2g0ps = (u16*)((char*)d_out + 50331648ull); // 1 MB prep temp (dead later)
    u16*   W1g0T  = (u16*)((char*)d_out + 51380224ull); // 1 MB prep temp (dead later)

    const int BIG = 1 << 30;
    dim3 tb(32, 8);

    // prep
    transpose_k<<<dim3(512, 16, 2), tb, 0, stream>>>(x_in, XF, XBb, 512, 16384, 8388608, 8388608);
    transpose_k<<<dim3(16, 16, 2), tb, 0, stream>>>(Wq, nullptr, WQK, 512, 512, 262144, 524288);
    transpose_k<<<dim3(16, 16, 2), tb, 0, stream>>>(Wk, nullptr, WQK + 262144, 512, 512, 262144, 524288);
    transpose_k<<<dim3(16, 16, 2), tb, 0, stream>>>(Wv, nullptr, WVt, 512, 512, 262144, 262144);
    cvt_bf16_k<<<2048, 256, 0, stream>>>(w1, W1b);
    // FFN weight prep: W2b cols 0..1535 = w2 cols 512..2047 ([g1|g2|g3]);
    // cols 1536..2047 = M0 = (w2 g0-cols * (1+dw1)) @ w1_g0^T (fused g0 path)
    cvtw2_k<<<1536, 256, 0, stream>>>(w2, W2b);
    cvtw2g0_k<<<512, 256, 0, stream>>>(w2, dw1, W2g0ps);
    transpose_k<<<dim3(16, 16, 2), tb, 0, stream>>>(w1, nullptr, W1g0T, 512, 512, 1048576, 262144);
    for (int l = 0; l < 2; l++)
        gemm_nt_k<64, 128><<<dim3(4, 8), 256, 0, stream>>>(W2g0ps + l * 262144,
            W1g0T + l * 262144, 512, 512, 2048, BIG, 0, 0,
            nullptr, nullptr, nullptr, W2b + l * 1048576 + 1536, nullptr);

    for (int l = 0; l < 2; l++) {
        // XT (bf16 [b][c][n]) into R2
        if (l == 0)
            cvt_bf16_k<<<16384, 256, 0, stream>>>(x_in, R2);
        else
            transpose16_k<<<dim3(16, 512, 2), tb, 0, stream>>>(XBb, R2, 16384, 512, 8388608, 8388608);
        // S = X^T X per batch: split-K partials (z=16 -> 2 blocks/CU)
        gemm5_k<<<dim3(4, 8, 16), 512, 0, stream>>>(R2, R2, 16384, 16384, 512,
            512, 8388608, 1024, nullptr, nullptr, Sp, nullptr, nullptr, nullptr);
        sreduce_k<<<2048, 256, 0, stream>>>(Sp, Sbf);
        // T12 = S @ [Wq|Wk]^T  (one N=1024 GEMM into T12f [1024][1024])
        gemm_nt_k<64, 128><<<dim3(8, 16), 256, 0, stream>>>(Sbf, WQK + l * 524288,
            512, 512, 1024, BIG, 0, 0, nullptr, nullptr, T12f, nullptr, nullptr);
        nrm_k<<<8, 256, 0, stream>>>(Wq + l * 262144, Wk + l * 262144, T12f, QNI, KNI);
        gsmall_k<<<dim3(8, 2), 256, 0, stream>>>(T12f + 512, Wq + l * 262144, QNI, KNI,
            resc + l * 8, ATT);
        mbuild_k<<<dim3(8, 2, 8), 256, 0, stream>>>(ATT, projW + l * 262144, Mnt);
        // V = x @ Wv  (512-thread 128x128)
        gemm5_k<<<dim3(4, 256), 512, 0, stream>>>(XBb, WVt + l * 262144, 512, 512, 512,
            BIG, 0, 0, nullptr, nullptr, nullptr, R3, nullptr, nullptr);
        // positional branch FIRST: conv3+gelu (R3->R2), conv3 -> bf16 P (XBb)
        dwreg_k<3, 16, 4, true, false, false, 512, 512><<<dim3(64, 8, 2), 256, 0, stream>>>(
            R3, posw1 + l * 4608, R2, nullptr);
        dwreg_k<3, 16, 4, false, false, false, 512, 512><<<dim3(64, 8, 2), 256, 0, stream>>>(
            R2, posw2 + l * 4608, XBb, nullptr);
        // x += V @ M^T + proj_b + P   (512-thread, single XF RMW pass)
        gemm5_k<<<dim3(4, 256), 512, 0, stream>>>(R3, Mnt, 512, 512, 512,
            16384, 262144, 0, projB + l * 512, XF, XF, nullptr, XBb, nullptr);
        // PreNorm
        ln_k<<<8192, 256, 0, stream>>>(XF, lng + l * 512, lnb + l * 512, XBb);
        // MS-FFN: per-batch slabs. ONE N=1536 up-GEMM (g1,g2,g3 = contiguous
        // W1b rows 512..2047) -> Y2 slots 1,2,3 raw; conv cascade through
        // freed slots: conv3 1->0, conv5 2->1, conv7 3->2; xcopy xn -> slot3
        // (race-free: A entirely from Y2 while outB writes XBb).
        for (int b2 = 0; b2 < 2; b2++) {
            const size_t boff = (size_t)b2 * NPIX * 512;
            const u16* w1l = W1b + l * 1048576;
            // up g1+g2+g3 (N=1536) -> slots 1,2,3
            gemm5_k<<<dim3(12, 128), 512, 0, stream>>>(XBb + boff,
                w1l + 512 * 512, 512, 512, 2048,
                BIG, 0, 0, nullptr, nullptr, nullptr, Y2 + 512, nullptr, nullptr);
            // conv3: slot1 (raw g1) -> slot0
            dwreg_k<3, 16, 4, false, true, false, 2048, 2048><<<dim3(64, 8, 1), 256, 0, stream>>>(
                Y2 + 512, dw3 + l * 4608, Y2 + 0, nullptr);
            // conv5: slot2 (raw g2) -> slot1
            dwreg_k<5, 16, 2, false, true, false, 2048, 2048><<<dim3(128, 8, 1), 256, 0, stream>>>(
                Y2 + 1024, dw5 + l * 12800, Y2 + 512, nullptr);
            // conv7: slot3 (raw g3) -> slot2
            dwreg_k<7, 32, 2, false, true, false, 2048, 2048><<<dim3(128, 4, 1), 256, 0, stream>>>(
                Y2 + 1536, dw7 + l * 25088, Y2 + 1024, nullptr);
            // xn -> slot3 (feeds the M0 columns; conv7's slot3 reads are done)
            xcopy_k<<<4096, 256, 0, stream>>>(XBb + boff, Y2);
            // single K=2048 down-GEMM: XF += Y2 @ W2b^T  (W2b = [g1|g2|g3|M0])
            gemm5_k<<<dim3(4, 128), 512, 0, stream>>>(Y2,
                W2b + l * 1048576, 2048, 2048, 512,
                BIG, 0, 0, nullptr, XF + boff, XF + boff, XBb + boff, nullptr, nullptr);
        }
    }
    // final: XF [b,n,c] -> out [b,c,n]
    transpose_k<<<dim3(16, 512, 2), tb, 0, stream>>>(XF, out, nullptr, 16384, 512, 8388608, 8388608);
}